// Round 1
// baseline (97.298 us; speedup 1.0000x reference)
//
#include <hip/hip_runtime.h>

#define NIN 784
#define WIDTH 1024
#define HALF 512
#define DEPTH 8
#define BDEPTH 10
#define BATCH 4096
#define SPLINE_DIM 20

// Clamped knot vector T[23]: [-8]*3, +-2^k/32 ladder, 0, [8]*3
__device__ float d_T[23] = {
  -8.f, -8.f, -8.f, -4.f, -2.f, -1.f, -0.5f, -0.25f, -0.125f, -0.0625f,
  -0.03125f, 0.f, 0.03125f, 0.0625f, 0.125f, 0.25f, 0.5f, 1.f, 2.f, 4.f,
  8.f, 8.f, 8.f };

// ---------------------------------------------------------------------------
// Prep kernel: build
//  (a) cs[(i*10+d)*1024 + slot] = (cos theta, +-sin theta), sign folded by the
//      slot's partner polarity (n9) at step d. Slot bits: [r3 r2 r1 r0 | lane5..0].
//      Logical element index at step d: n_b = slot bit (b-d mod 10).
//  (b) c3[(i*18+mi)*512 + w] = {coef[w][mi], coef[w][mi+1], coef[w][mi+2], 0}
// ---------------------------------------------------------------------------
__global__ void prep_kernel(const float* __restrict__ bp,
                            const float* __restrict__ sc,
                            float2* __restrict__ cs,
                            float4* __restrict__ c3) {
  int gid = blockIdx.x * 256 + threadIdx.x;
  if (gid < DEPTH * BDEPTH * 1024) {
    int slot = gid & 1023;
    int d = (gid >> 10) % BDEPTH;
    int i = gid / (BDEPTH * 1024);
    int n = 0;
#pragma unroll
    for (int b = 0; b < 10; ++b) {
      int src = b - d; if (src < 0) src += 10;
      n |= ((slot >> src) & 1) << b;
    }
    int pj = n & 511;
    float theta = bp[(i * HALF + pj) * BDEPTH + d];
    float c = cosf(theta), s = sinf(theta);
    cs[gid] = make_float2(c, (n & 512) ? -s : s);
  }
  int gid2 = gid - DEPTH * BDEPTH * 1024;
  if (gid2 >= 0 && gid2 < (DEPTH - 1) * 18 * HALF) {
    int w = gid2 & 511;
    int mi = (gid2 >> 9) % 18;
    int i = gid2 / (18 * HALF);
    const float* row = sc + (i * HALF + w) * SPLINE_DIM;
    c3[gid2] = make_float4(row[mi], row[mi + 1], row[mi + 2], 0.f);
  }
}

// ---------------------------------------------------------------------------
// Local degree-2 B-spline evaluation: 3 nonzero basis values at x, dotted with
// the prepacked coefficient triple.
// ---------------------------------------------------------------------------
__device__ __forceinline__ float spline_act(float x, const float4* __restrict__ cL,
                                            int w, const float* __restrict__ Ts) {
  x = fminf(fmaxf(x, -8.0f), 7.999999f);
  float ax = fabsf(x);
  int m;
  if (ax < 0.03125f) {
    m = (x < 0.f) ? 10 : 11;
  } else {
    unsigned bits = __float_as_uint(ax);
    int e = (int)(bits >> 23) - 127;          // floor(log2(ax)), ax normalized
    if (x > 0.f) {
      m = 17 + e;                              // x in [2^e, 2^{e+1})
    } else {
      int ce = e + ((bits & 0x7fffffu) ? 1 : 0); // ceil(log2(ax))
      m = 5 - ce;
    }
  }
  float tm1 = Ts[m - 1], tm = Ts[m], tp1 = Ts[m + 1], tp2 = Ts[m + 2];
  float left1 = x - tm;
  float right1 = tp1 - x;
  float left2 = x - tm1;
  float right2 = tp2 - x;
  float inv1 = __builtin_amdgcn_rcpf(tp1 - tm);
  float N0 = right1 * inv1;
  float N1 = left1 * inv1;
  float temp0 = N0 * __builtin_amdgcn_rcpf(tp1 - tm1);
  float B0 = right1 * temp0;
  float saved = left2 * temp0;
  float temp1 = N1 * __builtin_amdgcn_rcpf(tp2 - tm);
  float B1 = fmaf(right2, temp1, saved);
  float B2 = left1 * temp1;
  float4 cf = cL[(m - 2) * HALF + w];
  return fmaf(B0, cf.x, fmaf(B1, cf.y, B2 * cf.z));
}

// ---------------------------------------------------------------------------
// Main kernel: one wave holds 2 rows (16 regs/row). Butterfly steps 0-3 are
// intra-lane reg pairings; steps 4-9 are lane-xor shuffles. No barriers in the
// hot loop; layout returns to identity after each 10-step butterfly.
// ---------------------------------------------------------------------------
__global__ __launch_bounds__(256, 2) void fwd_kernel(
    const float* __restrict__ X, const float2* __restrict__ cs,
    const float4* __restrict__ c3, float* __restrict__ out) {
  __shared__ float Ts[23];
  int tid = threadIdx.x;
  if (tid < 23) Ts[tid] = d_T[tid];
  __syncthreads();

  int lane = tid & 63;
  int wv = tid >> 6;                       // 0..3
  int row0 = blockIdx.x * 8 + wv * 2;

  const float* x0p = X + (long)row0 * NIN;
  const float* x1p = X + (long)(row0 + 1) * NIN;
  float s0[16], s1[16];
#pragma unroll
  for (int r = 0; r < 16; ++r) {
    int w = r * 64 + lane;
    bool in = (w < NIN);
    s0[r] = in ? x0p[w] : 0.f;
    s1[r] = in ? x1p[w] : 0.f;
  }

  for (int i = 0; i < DEPTH; ++i) {
    const float2* csL = cs + i * (BDEPTH * 1024);
    // steps 0..3: partner = reg ^ (8>>d), same lane
#pragma unroll
    for (int d = 0; d < 4; ++d) {
      const float2* cp = csL + d * 1024 + lane;
      const int mr = 8 >> d;
#pragma unroll
      for (int r = 0; r < 16; ++r) {
        if ((r & mr) == 0) {
          float2 v = cp[r * 64];
          float a0 = s0[r], b0 = s0[r + mr];
          s0[r]      = fmaf(a0, v.x, b0 * v.y);
          s0[r + mr] = fmaf(b0, v.x, -a0 * v.y);
          float a1 = s1[r], b1 = s1[r + mr];
          s1[r]      = fmaf(a1, v.x, b1 * v.y);
          s1[r + mr] = fmaf(b1, v.x, -a1 * v.y);
        }
      }
    }
    // steps 4..9: partner = lane ^ (32>>(d-4)), same reg
#pragma unroll
    for (int d = 4; d < 10; ++d) {
      const float2* cp = csL + d * 1024 + lane;
      const int ml = 32 >> (d - 4);
#pragma unroll
      for (int r = 0; r < 16; ++r) {
        float2 v = cp[r * 64];
        float p0 = __shfl_xor(s0[r], ml, 64);
        float p1 = __shfl_xor(s1[r], ml, 64);
        s0[r] = fmaf(s0[r], v.x, p0 * v.y);
        s1[r] = fmaf(s1[r], v.x, p1 * v.y);
      }
    }
    if (i != DEPTH - 1) {
      const float4* cL = c3 + i * (18 * HALF);
#pragma unroll
      for (int r = 8; r < 16; ++r) {
        int w = ((r - 8) << 6) | lane;
        s0[r - 8] += spline_act(s0[r], cL, w, Ts);
        s1[r - 8] += spline_act(s1[r], cL, w, Ts);
      }
    }
  }

  float* o0 = out + (long)row0 * NIN;
  float* o1 = out + (long)(row0 + 1) * NIN;
#pragma unroll
  for (int r = 0; r < 13; ++r) {
    int w = r * 64 + lane;
    if (w < NIN) { o0[w] = s0[r]; o1[w] = s1[r]; }
  }
}

extern "C" void kernel_launch(void* const* d_in, const int* in_sizes, int n_in,
                              void* d_out, int out_size, void* d_ws, size_t ws_size,
                              hipStream_t stream) {
  const float* X  = (const float*)d_in[0];
  const float* bp = (const float*)d_in[1];   // [8,512,10]
  const float* sc = (const float*)d_in[2];   // [7,512,20]
  float* out = (float*)d_out;

  float2* cs = (float2*)d_ws;                                   // 655,360 B
  float4* c3 = (float4*)((char*)d_ws + DEPTH * BDEPTH * 1024 * sizeof(float2)); // 1,032,192 B

  int prep_threads = DEPTH * BDEPTH * 1024 + (DEPTH - 1) * 18 * HALF; // 146,432
  prep_kernel<<<(prep_threads + 255) / 256, 256, 0, stream>>>(bp, sc, cs, c3);
  fwd_kernel<<<BATCH / 8, 256, 0, stream>>>(X, cs, c3, out);
}